// Round 6
// baseline (1233.369 us; speedup 1.0000x reference)
//
#include <hip/hip_runtime.h>
#include <hip/hip_bf16.h>

// LSTM B=256,T=512,I=64,H=256. 64 WGs x 1024 thr, 4-way j-split.
// Runtime XCD discovery (s_getreg HW_REG_XCC_ID) forms co-XCD quads; h
// exchange via sc0 through the shared XCD L2 (sc0 store FIRST, LLC mirror
// second), bounded-spin readers with permanent LLC fallback.

#define B_TOT 256
#define T_SEQ 512
#define NIN   64
#define HID   256
#define CHUNK 16
#define JSL   64            // j per WG (4-way split)
#define ROWB  768           // LDS act row stride bytes (320 f16 = 640B data)
#define NKK   10            // K = 320 = 10*32
#define NWG   64
#define SPIN_MAX 384

typedef _Float16 half8 __attribute__((ext_vector_type(8)));
typedef float    f32x4 __attribute__((ext_vector_type(4)));

__device__ __forceinline__ float fast_rcp(float x){ return __builtin_amdgcn_rcpf(x); }
__device__ __forceinline__ float sigf(float v){ return fast_rcp(1.0f+__expf(-v)); }
__device__ __forceinline__ float tanhf_fast(float v){ return 1.0f-2.0f*fast_rcp(__expf(2.0f*v)+1.0f); }
__device__ __forceinline__ unsigned short f2h_bits(float f){
    _Float16 h=(_Float16)f; return __builtin_bit_cast(unsigned short,h);
}

__global__ void __launch_bounds__(1024, 4)
lstm_scan(const float* __restrict__ x,
          const float* __restrict__ Wih,
          const float* __restrict__ Whh,
          const float* __restrict__ bih,
          const float* __restrict__ bhh,
          const float* __restrict__ Wfc,
          const float* __restrict__ bfc,
          float* __restrict__ out,
          unsigned* __restrict__ hdr,   // [8] xcd counts, [8]=arrivals
          unsigned* __restrict__ hq)    // [2][B_TOT][HID] tagged h words
{
    __shared__ __align__(16) char act[CHUNK*ROWB];   // [16 rows][320 f16] swizzled
    __shared__ float gl[CHUNK][4*JSL + 1];           // [16][257] gate pre-acts
    __shared__ unsigned sh_cm;

    const int tid  = threadIdx.x;
    const int w    = tid >> 6;       // wave 0..15 (= batch row in cell phase)
    const int lane = tid & 63;
    const int lr   = lane & 15;
    const int kg   = lane >> 4;

    // ---- XCD discovery & quad formation (tid 0), broadcast via LDS ----
    if (tid == 0) {
        // hwreg(HW_REG_XCC_ID=20, offset 0, width 8): imm=(7<<11)|(0<<6)|20
        unsigned myxcd = ((unsigned)__builtin_amdgcn_s_getreg(14356)) & 7u;
        unsigned slot  = atomicAdd(&hdr[myxcd], 1u);
        atomicAdd(&hdr[8], 1u);
        while (__hip_atomic_load(&hdr[8], __ATOMIC_RELAXED,
                                 __HIP_MEMORY_SCOPE_AGENT) < (unsigned)NWG) {}
        unsigned counts[8];
        #pragma unroll
        for (int i = 0; i < 8; ++i)
            counts[i] = __hip_atomic_load(&hdr[i], __ATOMIC_RELAXED,
                                          __HIP_MEMORY_SCOPE_AGENT);
        unsigned totalIntra = 0;
        #pragma unroll
        for (int i = 0; i < 8; ++i) totalIntra += counts[i] >> 2;
        unsigned qbx = 0, lbx = 0;
        for (unsigned i = 0; i < myxcd; ++i) {
            qbx += counts[i] >> 2;
            lbx += counts[i] & 3u;
        }
        const unsigned nqm = counts[myxcd] >> 2;
        unsigned chunk, member;
        if (slot < 4u*nqm) {                 // intra-XCD quad (fast path likely)
            chunk = qbx + (slot >> 2);
            member = slot & 3u;
        } else {                             // leftover quad (may span XCDs)
            const unsigned lo = lbx + (slot - 4u*nqm);
            chunk = totalIntra + (lo >> 2);
            member = lo & 3u;
        }
        sh_cm = (chunk << 2) | member;
    }
    __syncthreads();
    const unsigned cm = sh_cm;
    const int chunk = (int)(cm >> 2);
    const int jw    = (int)(cm & 3u);
    const int cb    = chunk * CHUNK;

    // this wave's 16 gate rows: n = gg*256 + jw*64 + (w&3)*16 + lr
    const int gg = w >> 2;
    const int n  = gg*HID + jw*JSL + (w & 3)*16 + lr;

    // ---- register-resident weight fragments (B operand), 40 VGPRs ----
    half8 wv[NKK];
    const float bias = bih[n] + bhh[n];
    #pragma unroll
    for (int kk = 0; kk < 2; ++kk)
        #pragma unroll
        for (int jj = 0; jj < 8; ++jj)
            wv[kk][jj] = (_Float16)Wih[n*NIN + kk*32 + kg*8 + jj];
    #pragma unroll
    for (int kk = 2; kk < NKK; ++kk)
        #pragma unroll
        for (int jj = 0; jj < 8; ++jj)
            wv[kk][jj] = (_Float16)Whh[n*HID + kk*32 + kg*8 + jj - NIN];

    // ---- init act: zeros (h_0 = 0) then x_0 ----
    for (int i = tid; i < CHUNK*ROWB/4; i += 1024) ((int*)act)[i] = 0;
    __syncthreads();
    {
        float x0 = x[((size_t)(cb + w)*T_SEQ + 0)*NIN + lane];
        *(unsigned short*)(act + w*ROWB + ((lane*2) ^ (w << 4))) = f2h_bits(x0);
    }
    __syncthreads();

    float cst = 0.f, hlast = 0.f;
    bool  fastp = true;

    const int pj1 = (jw + 1) & 3, pj2 = (jw + 2) & 3, pj3 = (jw + 3) & 3;

    for (int t = 0; t < T_SEQ; ++t) {
        const int tn = (t+1 < T_SEQ) ? t+1 : T_SEQ-1;
        const float xv = x[((size_t)(cb + w)*T_SEQ + tn)*NIN + lane];

        // A fragments from act (row lr, swizzled, conflict-free)
        half8 af[NKK];
        #pragma unroll
        for (int kk = 0; kk < NKK; ++kk) {
            const int off = (kk*64 + kg*16) ^ (lr << 4);
            af[kk] = *(const half8*)(act + lr*ROWB + off);
        }
        f32x4 acc = {bias, bias, bias, bias};
        #pragma unroll
        for (int kk = 0; kk < NKK; ++kk)
            acc = __builtin_amdgcn_mfma_f32_16x16x32_f16(af[kk], wv[kk], acc, 0, 0, 0);

        // scatter pre-activations: (row kg*4+r, col w*16+lr)
        #pragma unroll
        for (int r = 0; r < 4; ++r)
            gl[kg*4 + r][w*16 + lr] = acc[r];
        __syncthreads();   // B1: gl ready; af reads done -> act writable

        // cell update: thread owns (row=w, jloc=lane)
        const float iv = sigf(gl[w][          lane]);
        const float fv = sigf(gl[w][  JSL  + lane]);
        const float gv = tanhf_fast(gl[w][2*JSL + lane]);
        const float ov = sigf(gl[w][3*JSL + lane]);
        const float cc = fv*cst + iv*gv;
        cst = cc;
        const float hv = ov*tanhf_fast(cc);
        hlast = hv;
        const unsigned short h16 = f2h_bits(hv);

        const unsigned tgt = (unsigned)(t+1);
        unsigned* hb = hq + ((size_t)(tgt & 1u)*B_TOT + (cb + w))*HID;

        // publish: sc0 store FIRST (fast same-XCD L2 visibility, no remote
        // ack), agent-atomic LLC mirror SECOND (fallback path, off critical).
        {
            const unsigned word = (tgt << 16) | (unsigned)h16;
            unsigned* myp = hb + jw*JSL + lane;
            asm volatile("global_store_dword %0, %1, off sc0"
                         :: "v"(myp), "v"(word) : "memory");
            __hip_atomic_store(myp, word, __ATOMIC_RELAXED, __HIP_MEMORY_SCOPE_AGENT);
        }

        // own h + x_{t+1} into act while stores are in flight
        {
            const int c = NIN + jw*JSL + lane;
            *(unsigned short*)(act + w*ROWB + ((c*2) ^ (w << 4))) = h16;
            if (t < T_SEQ-1)
                *(unsigned short*)(act + w*ROWB + ((lane*2) ^ (w << 4))) = f2h_bits(xv);
        }

        // gather 3 partner words: sc0 poll (shared-L2), fallback to LLC loads
        unsigned v0, v1, v2;
        {
            const unsigned* a0 = hb + (pj1*JSL + lane);
            const unsigned* a1 = hb + (pj2*JSL + lane);
            const unsigned* a2 = hb + (pj3*JSL + lane);
            bool need = true;
            if (fastp) {
                int tries = 0;
                for (;;) {
                    asm volatile(
                        "global_load_dword %0, %3, off sc0\n\t"
                        "global_load_dword %1, %4, off sc0\n\t"
                        "global_load_dword %2, %5, off sc0\n\t"
                        "s_waitcnt vmcnt(0)"
                        : "=&v"(v0), "=&v"(v1), "=&v"(v2)
                        : "v"(a0), "v"(a1), "v"(a2)
                        : "memory");
                    if ((((v0>>16)^tgt)|((v1>>16)^tgt)|((v2>>16)^tgt)) == 0u) {
                        need = false; break;
                    }
                    if (++tries > SPIN_MAX) { fastp = false; break; }
                }
            }
            if (need) {
                for (;;) {
                    v0 = __hip_atomic_load(a0, __ATOMIC_RELAXED, __HIP_MEMORY_SCOPE_AGENT);
                    v1 = __hip_atomic_load(a1, __ATOMIC_RELAXED, __HIP_MEMORY_SCOPE_AGENT);
                    v2 = __hip_atomic_load(a2, __ATOMIC_RELAXED, __HIP_MEMORY_SCOPE_AGENT);
                    if ((((v0>>16)^tgt)|((v1>>16)^tgt)|((v2>>16)^tgt)) == 0u) break;
                }
            }
        }
        {
            const int c1 = NIN + pj1*JSL + lane;
            const int c2 = NIN + pj2*JSL + lane;
            const int c3 = NIN + pj3*JSL + lane;
            *(unsigned short*)(act + w*ROWB + ((c1*2) ^ (w << 4))) = (unsigned short)v0;
            *(unsigned short*)(act + w*ROWB + ((c2*2) ^ (w << 4))) = (unsigned short)v1;
            *(unsigned short*)(act + w*ROWB + ((c3*2) ^ (w << 4))) = (unsigned short)v2;
        }

        __syncthreads();   // B2: act ready for next step
    }

    // ---- final FC: partial dot over this WG's 64 j, atomicAdd into out ----
    {
        float v = Wfc[jw*JSL + lane] * hlast;
        if (jw == 0 && lane == 0) v += bfc[0];
        #pragma unroll
        for (int off = 32; off; off >>= 1) v += __shfl_down(v, off);
        if (lane == 0) atomicAdd(&out[cb + w], v);
    }
}

extern "C" void kernel_launch(void* const* d_in, const int* in_sizes, int n_in,
                              void* d_out, int out_size, void* d_ws, size_t ws_size,
                              hipStream_t stream)
{
    const float* x   = (const float*)d_in[0];
    const float* Wih = (const float*)d_in[1];
    const float* Whh = (const float*)d_in[2];
    const float* bih = (const float*)d_in[3];
    const float* bhh = (const float*)d_in[4];
    const float* Wfc = (const float*)d_in[5];
    const float* bfc = (const float*)d_in[6];
    float* out = (float*)d_out;

    unsigned* hdr = (unsigned*)d_ws;                      // 1 KB header
    unsigned* hq  = (unsigned*)((char*)d_ws + 1024);      // [2][256][256] words

    hipMemsetAsync(d_ws, 0, 1024 + (size_t)2*B_TOT*HID*sizeof(unsigned), stream);
    hipMemsetAsync(d_out, 0, out_size*sizeof(float), stream);
    lstm_scan<<<NWG, 1024, 0, stream>>>(x, Wih, Whh, bih, bhh, Wfc, bfc,
                                        out, hdr, hq);
}

// Round 7
// 1139.605 us; speedup vs baseline: 1.0823x; 1.0823x over previous
//
#include <hip/hip_runtime.h>
#include <hip/hip_bf16.h>

// LSTM B=256,T=512,I=64,H=256. 64 WGs x 1024 thr, 4-way j-split (round-3 core).
// Weights register-resident (40 VGPR/thread). Per-step h exchange via tagged
// words + relaxed agent atomics; NEW: 3-deep software-pipelined poll (9
// outstanding loads, counted vmcnt) to cut retry quantization from ~RT to ~RT/3.

#define B_TOT 256
#define T_SEQ 512
#define NIN   64
#define HID   256
#define CHUNK 16
#define JSL   64            // j per WG (4-way split)
#define ROWB  768           // LDS act row stride bytes (320 f16 = 640B data)
#define NKK   10            // K = 320 = 10*32
#define NWG   64

typedef _Float16 half8 __attribute__((ext_vector_type(8)));
typedef float    f32x4 __attribute__((ext_vector_type(4)));

__device__ __forceinline__ float fast_rcp(float x){ return __builtin_amdgcn_rcpf(x); }
__device__ __forceinline__ float sigf(float v){ return fast_rcp(1.0f+__expf(-v)); }
__device__ __forceinline__ float tanhf_fast(float v){ return 1.0f-2.0f*fast_rcp(__expf(2.0f*v)+1.0f); }
__device__ __forceinline__ unsigned short f2h_bits(float f){
    _Float16 h=(_Float16)f; return __builtin_bit_cast(unsigned short,h);
}
#define LDA(p) __hip_atomic_load((p), __ATOMIC_RELAXED, __HIP_MEMORY_SCOPE_AGENT)

__global__ void __launch_bounds__(1024, 4)
lstm_scan(const float* __restrict__ x,
          const float* __restrict__ Wih,
          const float* __restrict__ Whh,
          const float* __restrict__ bih,
          const float* __restrict__ bhh,
          const float* __restrict__ Wfc,
          const float* __restrict__ bfc,
          float* __restrict__ out,
          unsigned* __restrict__ hq)    // [2][B_TOT][HID] tagged h words
{
    __shared__ __align__(16) char act[CHUNK*ROWB];   // [16 rows][320 f16] swizzled
    __shared__ float gl[CHUNK][4*JSL + 1];           // [16][257] gate pre-acts

    const int tid  = threadIdx.x;
    const int w    = tid >> 6;       // wave 0..15 (= batch row in cell phase)
    const int lane = tid & 63;
    const int lr   = lane & 15;
    const int kg   = lane >> 4;
    const int chunk= blockIdx.x & 15;
    const int jw   = blockIdx.x >> 4;    // 0..3
    const int cb   = chunk*CHUNK;

    // this wave's 16 gate rows: n = gg*256 + jw*64 + (w&3)*16 + lr
    const int gg = w >> 2;
    const int n  = gg*HID + jw*JSL + (w & 3)*16 + lr;

    // ---- register-resident weight fragments (B operand), 40 VGPRs ----
    half8 wv[NKK];
    const float bias = bih[n] + bhh[n];
    #pragma unroll
    for (int kk = 0; kk < 2; ++kk)
        #pragma unroll
        for (int jj = 0; jj < 8; ++jj)
            wv[kk][jj] = (_Float16)Wih[n*NIN + kk*32 + kg*8 + jj];
    #pragma unroll
    for (int kk = 2; kk < NKK; ++kk)
        #pragma unroll
        for (int jj = 0; jj < 8; ++jj)
            wv[kk][jj] = (_Float16)Whh[n*HID + kk*32 + kg*8 + jj - NIN];

    // ---- init act: zeros (h_0 = 0) then x_0 ----
    for (int i = tid; i < CHUNK*ROWB/4; i += 1024) ((int*)act)[i] = 0;
    __syncthreads();
    {
        float x0 = x[((size_t)(cb + w)*T_SEQ + 0)*NIN + lane];
        *(unsigned short*)(act + w*ROWB + ((lane*2) ^ (w << 4))) = f2h_bits(x0);
    }
    __syncthreads();

    float cst = 0.f, hlast = 0.f;

    const int pj1 = (jw + 1) & 3, pj2 = (jw + 2) & 3, pj3 = (jw + 3) & 3;

    for (int t = 0; t < T_SEQ; ++t) {
        const int tn = (t+1 < T_SEQ) ? t+1 : T_SEQ-1;
        const float xv = x[((size_t)(cb + w)*T_SEQ + tn)*NIN + lane];

        // A fragments from act (row lr, swizzled, conflict-free)
        half8 af[NKK];
        #pragma unroll
        for (int kk = 0; kk < NKK; ++kk) {
            const int off = (kk*64 + kg*16) ^ (lr << 4);
            af[kk] = *(const half8*)(act + lr*ROWB + off);
        }
        f32x4 acc = {bias, bias, bias, bias};
        #pragma unroll
        for (int kk = 0; kk < NKK; ++kk)
            acc = __builtin_amdgcn_mfma_f32_16x16x32_f16(af[kk], wv[kk], acc, 0, 0, 0);

        // scatter pre-activations: (row kg*4+r, col w*16+lr)
        #pragma unroll
        for (int r = 0; r < 4; ++r)
            gl[kg*4 + r][w*16 + lr] = acc[r];
        __syncthreads();   // B1: gl ready; af reads done -> act writable

        // cell update: thread owns (row=w, jloc=lane)
        const float iv = sigf(gl[w][          lane]);
        const float fv = sigf(gl[w][  JSL  + lane]);
        const float gv = tanhf_fast(gl[w][2*JSL + lane]);
        const float ov = sigf(gl[w][3*JSL + lane]);
        const float cc = fv*cst + iv*gv;
        cst = cc;
        const float hv = ov*tanhf_fast(cc);
        hlast = hv;
        const unsigned short h16 = f2h_bits(hv);

        const unsigned tgt = (unsigned)(t+1);
        unsigned* hb = hq + ((size_t)(tgt & 1u)*B_TOT + (cb + w))*HID;

        // publish (single relaxed agent-scope store -> coherent point)
        __hip_atomic_store(hb + jw*JSL + lane, (tgt << 16) | (unsigned)h16,
                           __ATOMIC_RELAXED, __HIP_MEMORY_SCOPE_AGENT);

        // own h + x_{t+1} into act while the publish round-trips
        {
            const int c = NIN + jw*JSL + lane;
            *(unsigned short*)(act + w*ROWB + ((c*2) ^ (w << 4))) = h16;
            if (t < T_SEQ-1)
                *(unsigned short*)(act + w*ROWB + ((lane*2) ^ (w << 4))) = f2h_bits(xv);
        }

        // gather 3 partner words: 3-deep pipelined tagged poll.
        // 9 relaxed loads outstanding; checking the oldest set needs only
        // vmcnt(6), so check period ~ RT/3 instead of RT.
        unsigned v0, v1, v2;
        {
            const unsigned* a0 = hb + (pj1*JSL + lane);
            const unsigned* a1 = hb + (pj2*JSL + lane);
            const unsigned* a2 = hb + (pj3*JSL + lane);
            unsigned A0=LDA(a0), A1=LDA(a1), A2=LDA(a2);
            unsigned B0=LDA(a0), B1=LDA(a1), B2=LDA(a2);
            unsigned C0=LDA(a0), C1=LDA(a1), C2=LDA(a2);
            for (;;) {
                if ((((A0>>16)^tgt)|((A1>>16)^tgt)|((A2>>16)^tgt)) == 0u) {
                    v0=A0; v1=A1; v2=A2; break;
                }
                A0=LDA(a0); A1=LDA(a1); A2=LDA(a2);
                if ((((B0>>16)^tgt)|((B1>>16)^tgt)|((B2>>16)^tgt)) == 0u) {
                    v0=B0; v1=B1; v2=B2; break;
                }
                B0=LDA(a0); B1=LDA(a1); B2=LDA(a2);
                if ((((C0>>16)^tgt)|((C1>>16)^tgt)|((C2>>16)^tgt)) == 0u) {
                    v0=C0; v1=C1; v2=C2; break;
                }
                C0=LDA(a0); C1=LDA(a1); C2=LDA(a2);
            }
        }
        {
            const int c1 = NIN + pj1*JSL + lane;
            const int c2 = NIN + pj2*JSL + lane;
            const int c3 = NIN + pj3*JSL + lane;
            *(unsigned short*)(act + w*ROWB + ((c1*2) ^ (w << 4))) = (unsigned short)v0;
            *(unsigned short*)(act + w*ROWB + ((c2*2) ^ (w << 4))) = (unsigned short)v1;
            *(unsigned short*)(act + w*ROWB + ((c3*2) ^ (w << 4))) = (unsigned short)v2;
        }

        __syncthreads();   // B2: act ready for next step
    }

    // ---- final FC: partial dot over this WG's 64 j, atomicAdd into out ----
    {
        float v = Wfc[jw*JSL + lane] * hlast;
        if (jw == 0 && lane == 0) v += bfc[0];
        #pragma unroll
        for (int off = 32; off; off >>= 1) v += __shfl_down(v, off);
        if (lane == 0) atomicAdd(&out[cb + w], v);
    }
}

extern "C" void kernel_launch(void* const* d_in, const int* in_sizes, int n_in,
                              void* d_out, int out_size, void* d_ws, size_t ws_size,
                              hipStream_t stream)
{
    const float* x   = (const float*)d_in[0];
    const float* Wih = (const float*)d_in[1];
    const float* Whh = (const float*)d_in[2];
    const float* bih = (const float*)d_in[3];
    const float* bhh = (const float*)d_in[4];
    const float* Wfc = (const float*)d_in[5];
    const float* bfc = (const float*)d_in[6];
    float* out = (float*)d_out;

    unsigned* hq = (unsigned*)d_ws;   // [2][256][256] tagged words

    hipMemsetAsync(hq, 0, (size_t)2*B_TOT*HID*sizeof(unsigned), stream);
    hipMemsetAsync(d_out, 0, out_size*sizeof(float), stream);
    lstm_scan<<<NWG, 1024, 0, stream>>>(x, Wih, Whh, bih, bhh, Wfc, bfc,
                                        out, hq);
}

// Round 8
// 821.760 us; speedup vs baseline: 1.5009x; 1.3868x over previous
//
#include <hip/hip_runtime.h>
#include <hip/hip_bf16.h>

// LSTM B=256,T=512,I=64,H=256. 64 WGs x 1024 thr, 4-way j-split (round-3 core).
// Weights register-resident (40 VGPR/thread). Per-step h exchange via tagged
// words; NEW: exchange uses LLC-executed atomic RMW (atomicExch publish,
// atomicOr-0 poll) so the traffic stays resident at the LLC instead of
// write-through/refetch at HBM (round-7 counters: FETCH~=WRITE~=134MB).

#define B_TOT 256
#define T_SEQ 512
#define NIN   64
#define HID   256
#define CHUNK 16
#define JSL   64            // j per WG (4-way split)
#define ROWB  768           // LDS act row stride bytes (320 f16 = 640B data)
#define NKK   10            // K = 320 = 10*32
#define NWG   64

typedef _Float16 half8 __attribute__((ext_vector_type(8)));
typedef float    f32x4 __attribute__((ext_vector_type(4)));

__device__ __forceinline__ float fast_rcp(float x){ return __builtin_amdgcn_rcpf(x); }
__device__ __forceinline__ float sigf(float v){ return fast_rcp(1.0f+__expf(-v)); }
__device__ __forceinline__ float tanhf_fast(float v){ return 1.0f-2.0f*fast_rcp(__expf(2.0f*v)+1.0f); }
__device__ __forceinline__ unsigned short f2h_bits(float f){
    _Float16 h=(_Float16)f; return __builtin_bit_cast(unsigned short,h);
}
// LLC-executed RMW read: returns current value, line stays LLC-resident
#define LDRMW(p) __hip_atomic_fetch_or((p), 0u, __ATOMIC_RELAXED, __HIP_MEMORY_SCOPE_AGENT)

__global__ void __launch_bounds__(1024, 4)
lstm_scan(const float* __restrict__ x,
          const float* __restrict__ Wih,
          const float* __restrict__ Whh,
          const float* __restrict__ bih,
          const float* __restrict__ bhh,
          const float* __restrict__ Wfc,
          const float* __restrict__ bfc,
          float* __restrict__ out,
          unsigned* __restrict__ hq)    // [2][B_TOT][HID] tagged h words
{
    __shared__ __align__(16) char act[CHUNK*ROWB];   // [16 rows][320 f16] swizzled
    __shared__ float gl[CHUNK][4*JSL + 1];           // [16][257] gate pre-acts

    const int tid  = threadIdx.x;
    const int w    = tid >> 6;       // wave 0..15 (= batch row in cell phase)
    const int lane = tid & 63;
    const int lr   = lane & 15;
    const int kg   = lane >> 4;
    const int chunk= blockIdx.x & 15;
    const int jw   = blockIdx.x >> 4;    // 0..3
    const int cb   = chunk*CHUNK;

    // this wave's 16 gate rows: n = gg*256 + jw*64 + (w&3)*16 + lr
    const int gg = w >> 2;
    const int n  = gg*HID + jw*JSL + (w & 3)*16 + lr;

    // ---- register-resident weight fragments (B operand), 40 VGPRs ----
    half8 wv[NKK];
    const float bias = bih[n] + bhh[n];
    #pragma unroll
    for (int kk = 0; kk < 2; ++kk)
        #pragma unroll
        for (int jj = 0; jj < 8; ++jj)
            wv[kk][jj] = (_Float16)Wih[n*NIN + kk*32 + kg*8 + jj];
    #pragma unroll
    for (int kk = 2; kk < NKK; ++kk)
        #pragma unroll
        for (int jj = 0; jj < 8; ++jj)
            wv[kk][jj] = (_Float16)Whh[n*HID + kk*32 + kg*8 + jj - NIN];

    // ---- init act: zeros (h_0 = 0) then x_0 ----
    for (int i = tid; i < CHUNK*ROWB/4; i += 1024) ((int*)act)[i] = 0;
    __syncthreads();
    {
        float x0 = x[((size_t)(cb + w)*T_SEQ + 0)*NIN + lane];
        *(unsigned short*)(act + w*ROWB + ((lane*2) ^ (w << 4))) = f2h_bits(x0);
    }
    __syncthreads();

    float cst = 0.f, hlast = 0.f;

    const int pj1 = (jw + 1) & 3, pj2 = (jw + 2) & 3, pj3 = (jw + 3) & 3;

    for (int t = 0; t < T_SEQ; ++t) {
        const int tn = (t+1 < T_SEQ) ? t+1 : T_SEQ-1;
        const float xv = x[((size_t)(cb + w)*T_SEQ + tn)*NIN + lane];

        // A fragments from act (row lr, swizzled, conflict-free)
        half8 af[NKK];
        #pragma unroll
        for (int kk = 0; kk < NKK; ++kk) {
            const int off = (kk*64 + kg*16) ^ (lr << 4);
            af[kk] = *(const half8*)(act + lr*ROWB + off);
        }
        f32x4 acc = {bias, bias, bias, bias};
        #pragma unroll
        for (int kk = 0; kk < NKK; ++kk)
            acc = __builtin_amdgcn_mfma_f32_16x16x32_f16(af[kk], wv[kk], acc, 0, 0, 0);

        // scatter pre-activations: (row kg*4+r, col w*16+lr)
        #pragma unroll
        for (int r = 0; r < 4; ++r)
            gl[kg*4 + r][w*16 + lr] = acc[r];
        __syncthreads();   // B1: gl ready; af reads done -> act writable

        // cell update: thread owns (row=w, jloc=lane)
        const float iv = sigf(gl[w][          lane]);
        const float fv = sigf(gl[w][  JSL  + lane]);
        const float gv = tanhf_fast(gl[w][2*JSL + lane]);
        const float ov = sigf(gl[w][3*JSL + lane]);
        const float cc = fv*cst + iv*gv;
        cst = cc;
        const float hv = ov*tanhf_fast(cc);
        hlast = hv;
        const unsigned short h16 = f2h_bits(hv);

        const unsigned tgt = (unsigned)(t+1);
        unsigned* hb = hq + ((size_t)(tgt & 1u)*B_TOT + (cb + w))*HID;

        // publish: atomicExch -> RMW executed AT the LLC, line stays resident
        (void)__hip_atomic_exchange(hb + jw*JSL + lane,
                                    (tgt << 16) | (unsigned)h16,
                                    __ATOMIC_RELAXED, __HIP_MEMORY_SCOPE_AGENT);

        // own h + x_{t+1} into act while the publish round-trips
        {
            const int c = NIN + jw*JSL + lane;
            *(unsigned short*)(act + w*ROWB + ((c*2) ^ (w << 4))) = h16;
            if (t < T_SEQ-1)
                *(unsigned short*)(act + w*ROWB + ((lane*2) ^ (w << 4))) = f2h_bits(xv);
        }

        // gather 3 partner words: tagged poll via LLC-executed RMW reads
        unsigned v0, v1, v2;
        {
            unsigned* a0 = hb + (pj1*JSL + lane);
            unsigned* a1 = hb + (pj2*JSL + lane);
            unsigned* a2 = hb + (pj3*JSL + lane);
            for (;;) {
                v0 = LDRMW(a0);
                v1 = LDRMW(a1);
                v2 = LDRMW(a2);
                if ((((v0>>16)^tgt)|((v1>>16)^tgt)|((v2>>16)^tgt)) == 0u) break;
            }
        }
        {
            const int c1 = NIN + pj1*JSL + lane;
            const int c2 = NIN + pj2*JSL + lane;
            const int c3 = NIN + pj3*JSL + lane;
            *(unsigned short*)(act + w*ROWB + ((c1*2) ^ (w << 4))) = (unsigned short)v0;
            *(unsigned short*)(act + w*ROWB + ((c2*2) ^ (w << 4))) = (unsigned short)v1;
            *(unsigned short*)(act + w*ROWB + ((c3*2) ^ (w << 4))) = (unsigned short)v2;
        }

        __syncthreads();   // B2: act ready for next step
    }

    // ---- final FC: partial dot over this WG's 64 j, atomicAdd into out ----
    {
        float v = Wfc[jw*JSL + lane] * hlast;
        if (jw == 0 && lane == 0) v += bfc[0];
        #pragma unroll
        for (int off = 32; off; off >>= 1) v += __shfl_down(v, off);
        if (lane == 0) atomicAdd(&out[cb + w], v);
    }
}

extern "C" void kernel_launch(void* const* d_in, const int* in_sizes, int n_in,
                              void* d_out, int out_size, void* d_ws, size_t ws_size,
                              hipStream_t stream)
{
    const float* x   = (const float*)d_in[0];
    const float* Wih = (const float*)d_in[1];
    const float* Whh = (const float*)d_in[2];
    const float* bih = (const float*)d_in[3];
    const float* bhh = (const float*)d_in[4];
    const float* Wfc = (const float*)d_in[5];
    const float* bfc = (const float*)d_in[6];
    float* out = (float*)d_out;

    unsigned* hq = (unsigned*)d_ws;   // [2][256][256] tagged words

    hipMemsetAsync(hq, 0, (size_t)2*B_TOT*HID*sizeof(unsigned), stream);
    hipMemsetAsync(d_out, 0, out_size*sizeof(float), stream);
    lstm_scan<<<NWG, 1024, 0, stream>>>(x, Wih, Whh, bih, bhh, Wfc, bfc,
                                        out, hq);
}